// Round 4
// baseline (323.600 us; speedup 1.0000x reference)
//
#include <hip/hip_runtime.h>
#include <math.h>

#define D_INN 256
#define D_HID 64
#define DTR 16
#define D_MEMM 128
#define BB 2
#define LL 2048
#define NROWS (BB*LL)   // 4096
#define NPROJ 736
#define NTOT 864        // 736 proj cols + 128 Q cols
#define SEG 16
#define SEGLEN (LL/SEG) // 128

typedef __attribute__((ext_vector_type(8))) short short8v;
typedef __attribute__((ext_vector_type(4))) float float4v;

static __device__ __forceinline__ unsigned short f2bf(float f) {
    unsigned int u = __float_as_uint(f);
    u += 0x7fff + ((u >> 16) & 1);   // RNE
    return (unsigned short)(u >> 16);
}

// ---------------- Kernel 1: proj = x @ [W_xproj | W_Q] (+b_Q), bf16 MFMA ----------------
// 64x64 tile, BK=32, 4 waves (2x2 quadrants of 32x32), mfma_f32_16x16x32_bf16.
__global__ __launch_bounds__(256) void k_gemm(const float* __restrict__ x,
        const float* __restrict__ Wx, const float* __restrict__ Wq,
        const float* __restrict__ bq, float* __restrict__ proj) {
    __shared__ unsigned short As[64][40];   // [row][k], 80B row stride (16B aligned)
    __shared__ unsigned short Bs[64][40];   // [col][k]
    const int t = threadIdx.x;
    const int lane = t & 63, w = t >> 6;
    const int wr = w >> 1, wc = w & 1;
    const int row0 = blockIdx.y * 64, col0 = blockIdx.x * 64;

    float4v acc[2][2];
    #pragma unroll
    for (int i = 0; i < 2; i++)
        #pragma unroll
        for (int j = 0; j < 2; j++) acc[i][j] = (float4v)0.f;

    const int ar = t >> 2, akq = (t & 3) * 8;         // A: row, k-offset
    const int bk = t >> 3, bcq = (t & 7) * 8;         // B: k, col-offset

    for (int k0 = 0; k0 < D_INN; k0 += 32) {
        // global loads (f32) for this k-step
        float4 a0 = *(const float4*)&x[(size_t)(row0 + ar) * D_INN + k0 + akq];
        float4 a1 = *(const float4*)&x[(size_t)(row0 + ar) * D_INN + k0 + akq + 4];
        float4 b0 = {}, b1 = {};
        int col = col0 + bcq;
        if (col + 8 <= NPROJ) {
            b0 = *(const float4*)&Wx[(size_t)(k0 + bk) * NPROJ + col];
            b1 = *(const float4*)&Wx[(size_t)(k0 + bk) * NPROJ + col + 4];
        } else if (col < NTOT) {   // 8-aligned runs: entirely in Wq region
            b0 = *(const float4*)&Wq[(size_t)(k0 + bk) * D_MEMM + (col - NPROJ)];
            b1 = *(const float4*)&Wq[(size_t)(k0 + bk) * D_MEMM + (col - NPROJ) + 4];
        }
        __syncthreads();   // previous iteration's frag reads done
        {
            unsigned short av[8] = { f2bf(a0.x), f2bf(a0.y), f2bf(a0.z), f2bf(a0.w),
                                     f2bf(a1.x), f2bf(a1.y), f2bf(a1.z), f2bf(a1.w) };
            *(short8v*)&As[ar][akq] = *(short8v*)av;
            Bs[bcq + 0][bk] = f2bf(b0.x); Bs[bcq + 1][bk] = f2bf(b0.y);
            Bs[bcq + 2][bk] = f2bf(b0.z); Bs[bcq + 3][bk] = f2bf(b0.w);
            Bs[bcq + 4][bk] = f2bf(b1.x); Bs[bcq + 5][bk] = f2bf(b1.y);
            Bs[bcq + 6][bk] = f2bf(b1.z); Bs[bcq + 7][bk] = f2bf(b1.w);
        }
        __syncthreads();
        short8v af[2], bf[2];
        const int fr = lane & 15, fk = (lane >> 4) * 8;
        af[0] = *(short8v*)&As[wr * 32 + fr][fk];
        af[1] = *(short8v*)&As[wr * 32 + 16 + fr][fk];
        bf[0] = *(short8v*)&Bs[wc * 32 + fr][fk];
        bf[1] = *(short8v*)&Bs[wc * 32 + 16 + fr][fk];
        #pragma unroll
        for (int i = 0; i < 2; i++)
            #pragma unroll
            for (int j = 0; j < 2; j++)
                acc[i][j] = __builtin_amdgcn_mfma_f32_16x16x32_bf16(af[i], bf[j], acc[i][j], 0, 0, 0);
    }
    // epilogue: D row=(lane>>4)*4+e, col=lane&15
    #pragma unroll
    for (int i = 0; i < 2; i++)
        #pragma unroll
        for (int j = 0; j < 2; j++)
            #pragma unroll
            for (int e = 0; e < 4; e++) {
                int rr = row0 + wr * 32 + i * 16 + (lane >> 4) * 4 + e;
                int cc = col0 + wc * 32 + j * 16 + (lane & 15);
                if (cc < NTOT) {
                    float v = acc[i][j][e];
                    if (cc >= NPROJ) v += bq[cc - NPROJ];
                    proj[(size_t)rr * NTOT + cc] = v;
                }
            }
}

// ---------------- Kernel 2: delta / delta_l = softplus(dt @ W + b) ----------------
__global__ __launch_bounds__(256) void k_delta(const float* __restrict__ proj,
        const float* __restrict__ Wdt, const float* __restrict__ bdt,
        const float* __restrict__ Wdtl, const float* __restrict__ bdtl,
        float* __restrict__ delta, float* __restrict__ deltal) {
    __shared__ float sdt[16], sdtl[16];
    int row = blockIdx.x;
    int t = threadIdx.x;
    if (t < 16) sdt[t] = proj[(size_t)row * NTOT + 704 + t];
    else if (t < 32) sdtl[t - 16] = proj[(size_t)row * NTOT + 720 + (t - 16)];
    __syncthreads();
    float a1 = bdt[t], a2 = bdtl[t];
    #pragma unroll
    for (int r = 0; r < DTR; r++) {
        a1 += sdt[r] * Wdt[r * D_INN + t];
        a2 += sdtl[r] * Wdtl[r * D_INN + t];
    }
    delta[(size_t)row * D_INN + t]  = (a1 > 20.f) ? a1 : log1pf(expf(a1));
    deltal[(size_t)row * D_INN + t] = (a2 > 20.f) ? a2 : log1pf(expf(a2));
}

// ---------------- Kernel 3a: pass 1 — per-segment (sumδ, Q); scan1 also checkpoints ----
// grid (64, 2, 32 = scan*16+seg); block 256 = 4 waves; wave w -> d = d0+w, lane n.
__global__ __launch_bounds__(256) void k_scan1(const float* __restrict__ x,
        const float* __restrict__ proj, const float* __restrict__ A,
        const float* __restrict__ delta, const float* __restrict__ deltal,
        float* __restrict__ Qbuf, float* __restrict__ SDbuf,
        float* __restrict__ cumd, float* __restrict__ mem) {
    __shared__ float Bsh[2][16][64];
    __shared__ float dus[2][16][8];   // per li: (δ0,p0,δ1,p1,δ2,p2,δ3,p3), p=δ·u
    const int t = threadIdx.x;
    const int w = t >> 6, n = t & 63;
    const int b = blockIdx.y;
    const int scan = blockIdx.z >> 4, seg = blockIdx.z & 15;
    const int d0 = blockIdx.x * 4, d = d0 + w;
    const size_t rowbase = (size_t)b * LL + (size_t)seg * SEGLEN;
    const float* dsel = (scan == 0 ? delta : deltal);
    const int cB = (scan == 0) ? 0 : 64;
    const float Aln = A[d * D_HID + n] * 1.44269504f;
    const int lli = t >> 4, lc4 = (t & 15) * 4;

    float4 nB = {}, du0 = {}, du1 = {};
    nB = *(const float4*)&proj[(rowbase + lli) * NTOT + cB + lc4];
    if (t < 16) {
        float4 dv4 = *(const float4*)&dsel[(rowbase + t) * D_INN + d0];
        float4 uv4 = *(const float4*)&x[(rowbase + t) * D_INN + d0];
        du0 = make_float4(dv4.x, dv4.x * uv4.x, dv4.y, dv4.y * uv4.y);
        du1 = make_float4(dv4.z, dv4.z * uv4.z, dv4.w, dv4.w * uv4.w);
    }
    *(float4*)&Bsh[0][lli][lc4] = nB;
    if (t < 16) { *(float4*)&dus[0][t][0] = du0; *(float4*)&dus[0][t][4] = du1; }
    __syncthreads();

    float s = 0.f, sd = 0.f;
    for (int c = 0; c < SEGLEN / 16; ++c) {
        const int cur = c & 1;
        const bool hn = (c + 1 < SEGLEN / 16);
        if (hn) {
            size_t row = rowbase + (c + 1) * 16;
            nB = *(const float4*)&proj[(row + lli) * NTOT + cB + lc4];
            if (t < 16) {
                float4 dv4 = *(const float4*)&dsel[(row + t) * D_INN + d0];
                float4 uv4 = *(const float4*)&x[(row + t) * D_INN + d0];
                du0 = make_float4(dv4.x, dv4.x * uv4.x, dv4.y, dv4.y * uv4.y);
                du1 = make_float4(dv4.z, dv4.z * uv4.z, dv4.w, dv4.w * uv4.w);
            }
        }
        #pragma unroll
        for (int li = 0; li < 16; ++li) {
            float2 dp = *(const float2*)&dus[cur][li][2 * w];
            float Bv = Bsh[cur][li][n];
            float dA = exp2f(dp.x * Aln);
            s = fmaf(dA, s, dp.y * Bv);
            sd += dp.x;
            if (scan == 1 && li == 0) {   // checkpoint: global l = seg*128+c*16 ≡ 0 mod 16
                float v = s;
                #pragma unroll
                for (int off = 32; off >= 1; off >>= 1) v += __shfl_xor(v, off);
                if (n == 0) {
                    int k = seg * 8 + c;
                    mem[((size_t)b * 128 + k) * D_INN + d] = v;            // partial (local)
                    cumd[(((size_t)b * SEG + seg) * 8 + c) * D_INN + d] = sd;
                }
            }
        }
        if (hn) {
            const int nxt = cur ^ 1;
            *(float4*)&Bsh[nxt][lli][lc4] = nB;
            if (t < 16) { *(float4*)&dus[nxt][t][0] = du0; *(float4*)&dus[nxt][t][4] = du1; }
        }
        __syncthreads();
    }
    Qbuf[((((size_t)scan * 2 + b) * SEG + seg) * D_INN + d) * 64 + n] = s;
    if (n == 0) SDbuf[(((size_t)scan * 2 + b) * SEG + seg) * D_INN + d] = sd;
}

// ---------------- Kernel 3b: pass 2 — scan 0 only, emit y ----------------
__global__ __launch_bounds__(256) void k_scan2(const float* __restrict__ x,
        const float* __restrict__ proj, const float* __restrict__ A,
        const float* __restrict__ Dp, const float* __restrict__ delta,
        const float* __restrict__ Qbuf, const float* __restrict__ SDbuf,
        float* __restrict__ y) {
    __shared__ float Bsh[2][8][64];
    __shared__ float Csh[2][8][64];
    __shared__ float dus[2][8][8];
    __shared__ float xs[2][8][4];
    __shared__ float rbuf[4][8][65];
    const int t = threadIdx.x;
    const int w = t >> 6, n = t & 63;
    const int b = blockIdx.y, seg = blockIdx.z;
    const int d0 = blockIdx.x * 4, d = d0 + w;
    const size_t rowbase = (size_t)b * LL + (size_t)seg * SEGLEN;
    const float Aln = A[d * D_HID + n] * 1.44269504f;
    const float Dpv = Dp[d];
    const int lli = (t & 127) >> 4, lc4 = (t & 15) * 4;
    const bool isB = (t < 128);
    const int rli = n >> 3, g = n & 7;

    // s_in prefix over earlier segments (scan 0)
    float s = 0.f;
    for (int k = 0; k < seg; ++k) {
        float sdk = SDbuf[(((size_t)b * SEG + k) * D_INN + d)];
        float Qk = Qbuf[(((size_t)b * SEG + k) * D_INN + d) * 64 + n];
        s = fmaf(exp2f(sdk * Aln), s, Qk);
    }

    float4 nT = {}, du0 = {}, du1 = {}, nU = {};
    {
        size_t row = rowbase + lli;
        if (isB) nT = *(const float4*)&proj[row * NTOT + lc4];
        else nT = *(const float4*)&proj[row * NTOT + 128 + lc4];
        if (t < 8) {
            float4 dv4 = *(const float4*)&delta[(rowbase + t) * D_INN + d0];
            nU = *(const float4*)&x[(rowbase + t) * D_INN + d0];
            du0 = make_float4(dv4.x, dv4.x * nU.x, dv4.y, dv4.y * nU.y);
            du1 = make_float4(dv4.z, dv4.z * nU.z, dv4.w, dv4.w * nU.w);
        }
    }
    if (isB) *(float4*)&Bsh[0][lli][lc4] = nT;
    else *(float4*)&Csh[0][lli][lc4] = nT;
    if (t < 8) {
        *(float4*)&dus[0][t][0] = du0; *(float4*)&dus[0][t][4] = du1;
        *(float4*)&xs[0][t][0] = nU;
    }
    __syncthreads();

    for (int c = 0; c < SEGLEN / 8; ++c) {
        const int cur = c & 1;
        const bool hn = (c + 1 < SEGLEN / 8);
        if (hn) {
            size_t row = rowbase + (c + 1) * 8 + lli;
            if (isB) nT = *(const float4*)&proj[row * NTOT + lc4];
            else nT = *(const float4*)&proj[row * NTOT + 128 + lc4];
            if (t < 8) {
                size_t r2 = rowbase + (c + 1) * 8 + t;
                float4 dv4 = *(const float4*)&delta[r2 * D_INN + d0];
                nU = *(const float4*)&x[r2 * D_INN + d0];
                du0 = make_float4(dv4.x, dv4.x * nU.x, dv4.y, dv4.y * nU.y);
                du1 = make_float4(dv4.z, dv4.z * nU.z, dv4.w, dv4.w * nU.w);
            }
        }
        #pragma unroll
        for (int li = 0; li < 8; ++li) {
            float2 dp = *(const float2*)&dus[cur][li][2 * w];
            float Bv = Bsh[cur][li][n];
            float dA = exp2f(dp.x * Aln);
            s = fmaf(dA, s, dp.y * Bv);
            rbuf[w][li][n] = s * Csh[cur][li][n];
        }
        {   // same-wave reduce (no barrier needed)
            float acc = 0.f;
            #pragma unroll
            for (int j = 0; j < 8; ++j) acc += rbuf[w][rli][g * 8 + j];
            acc += __shfl_xor(acc, 1);
            acc += __shfl_xor(acc, 2);
            acc += __shfl_xor(acc, 4);
            if (g == 0) {
                float xv = xs[cur][rli][w];
                size_t row = rowbase + c * 8 + rli;
                y[row * D_INN + d] = acc + xv * Dpv;
            }
        }
        if (hn) {
            const int nxt = cur ^ 1;
            if (isB) *(float4*)&Bsh[nxt][lli][lc4] = nT;
            else *(float4*)&Csh[nxt][lli][lc4] = nT;
            if (t < 8) {
                *(float4*)&dus[nxt][t][0] = du0; *(float4*)&dus[nxt][t][4] = du1;
                *(float4*)&xs[nxt][t][0] = nU;
            }
        }
        __syncthreads();
    }
}

// ---------------- Kernel 3c: mem fixup — add exp2(Aln·cumδ)·s_in correction ----------------
// grid (4 dchunks, 16 seg, 2 b); block 256 = 4 waves; wave w -> 16 d values, lane n.
__global__ __launch_bounds__(256) void k_memfix(const float* __restrict__ A,
        const float* __restrict__ Qbuf, const float* __restrict__ SDbuf,
        const float* __restrict__ cumd, float* __restrict__ mem) {
    const int t = threadIdx.x, w = t >> 6, n = t & 63;
    const int seg = blockIdx.y, b = blockIdx.z;
    if (seg == 0) return;
    for (int i = 0; i < 16; ++i) {
        const int d = blockIdx.x * 64 + w * 16 + i;
        const float Aln = A[d * D_HID + n] * 1.44269504f;
        float sin_ = 0.f;   // scan=1 state entering this segment
        for (int k = 0; k < seg; ++k) {
            float sdk = SDbuf[(((size_t)(2 + b)) * SEG + k) * D_INN + d];
            float Qk = Qbuf[((((size_t)(2 + b)) * SEG + k) * D_INN + d) * 64 + n];
            sin_ = fmaf(exp2f(sdk * Aln), sin_, Qk);
        }
        #pragma unroll
        for (int ck = 0; ck < 8; ++ck) {
            float cum = cumd[(((size_t)b * SEG + seg) * 8 + ck) * D_INN + d];
            float v = exp2f(cum * Aln) * sin_;
            #pragma unroll
            for (int off = 32; off >= 1; off >>= 1) v += __shfl_xor(v, off);
            if (n == 0) mem[((size_t)b * 128 + seg * 8 + ck) * D_INN + d] += v;
        }
    }
}

// ---------------- Kernel 4: K, V = memory @ W_K/V + b ----------------
__global__ __launch_bounds__(128) void k_kv(const float* __restrict__ mem,
        const float* __restrict__ Wk, const float* __restrict__ bk,
        const float* __restrict__ Wv, const float* __restrict__ bv,
        float* __restrict__ K, float* __restrict__ V) {
    __shared__ float mrow[256];
    int k = blockIdx.x, b = blockIdx.y;
    int t = threadIdx.x;
    const float* mr = mem + ((size_t)b * 128 + k) * D_INN;
    mrow[t] = mr[t];
    mrow[t + 128] = mr[t + 128];
    __syncthreads();
    float aK = bk[t], aV = bv[t];
    for (int dd = 0; dd < D_INN; dd++) {
        float m = mrow[dd];
        aK += m * Wk[dd * D_MEMM + t];
        aV += m * Wv[dd * D_MEMM + t];
    }
    K[((size_t)b * 128 + k) * D_MEMM + t] = aK;
    V[((size_t)b * 128 + k) * D_MEMM + t] = aV;
}

// ---------------- Kernel 5: attention + epilogue (all 256 threads active) ----------------
__global__ __launch_bounds__(256) void k_attn(const float* __restrict__ x,
        const float* __restrict__ proj, const float* __restrict__ y,
        const float* __restrict__ K, const float* __restrict__ V,
        const float* __restrict__ Wo, const float* __restrict__ bo,
        float* __restrict__ out) {
    __shared__ float q[128], part[2][128], sc[128], att[128];
    __shared__ float red[4];
    int l = blockIdx.x, b = blockIdx.y;
    size_t row = (size_t)b * LL + l;
    int t = threadIdx.x;
    if (t < 128) q[t] = proj[row * NTOT + NPROJ + t];
    __syncthreads();
    {   // QK: split each key's 128-dot across two waves
        int kk = t & 127, h = t >> 7;
        const float* Kr = K + ((size_t)b * 128 + kk) * D_MEMM + h * 64;
        const float* qh = q + h * 64;
        float a = 0.f;
        for (int m = 0; m < 64; m++) a += qh[m] * Kr[m];
        part[h][kk] = a;
    }
    __syncthreads();
    float scv = 0.f;
    if (t < 128) scv = (part[0][t] + part[1][t]) * 0.125f;   // 1/sqrt(64)
    float v = (t < 128) ? scv : -3.4e38f;
    #pragma unroll
    for (int o = 1; o < 64; o <<= 1) v = fmaxf(v, __shfl_xor(v, o));
    if ((t & 63) == 0 && t < 128) red[t >> 6] = v;
    __syncthreads();
    float mx = fmaxf(red[0], red[1]);
    float ex = 0.f;
    if (t < 128) { ex = expf(scv - mx); sc[t] = ex; }
    float sv = (t < 128) ? ex : 0.f;
    #pragma unroll
    for (int o = 1; o < 64; o <<= 1) sv += __shfl_xor(sv, o);
    if ((t & 63) == 0 && t < 128) red[2 + (t >> 6)] = sv;
    __syncthreads();
    float denom = red[2] + red[3];
    {   // wV: split each output's 128-sum across two waves
        int m = t & 127, h = t >> 7;
        const float* Vb = V + (size_t)b * 128 * D_MEMM + m + (size_t)h * 64 * D_MEMM;
        const float* sch = sc + h * 64;
        float a = 0.f;
        for (int k = 0; k < 64; k++) a += sch[k] * Vb[(size_t)k * D_MEMM];
        part[h][m] = a;
    }
    __syncthreads();
    if (t < 128) att[t] = (part[0][t] + part[1][t]) / denom;
    __syncthreads();
    float acc = bo[t];
    for (int m = 0; m < 128; m++) acc += att[m] * Wo[m * D_INN + t];
    float Ev = proj[row * NTOT + 192 + t];
    float Fv = proj[row * NTOT + 448 + t];
    out[row * D_INN + t] = y[row * D_INN + t] + acc * Ev + x[row * D_INN + t] * Fv;
}

extern "C" void kernel_launch(void* const* d_in, const int* in_sizes, int n_in,
                              void* d_out, int out_size, void* d_ws, size_t ws_size,
                              hipStream_t stream) {
    const float* x    = (const float*)d_in[0];
    const float* Wx   = (const float*)d_in[1];
    const float* Wdt  = (const float*)d_in[2];
    const float* bdt  = (const float*)d_in[3];
    const float* Wdtl = (const float*)d_in[4];
    const float* bdtl = (const float*)d_in[5];
    const float* A    = (const float*)d_in[6];
    const float* Dp   = (const float*)d_in[7];
    const float* Wq   = (const float*)d_in[8];
    const float* bq   = (const float*)d_in[9];
    const float* Wk   = (const float*)d_in[10];
    const float* bk   = (const float*)d_in[11];
    const float* Wv   = (const float*)d_in[12];
    const float* bv   = (const float*)d_in[13];
    const float* Wo   = (const float*)d_in[14];
    const float* bo   = (const float*)d_in[15];
    float* out = (float*)d_out;
    float* ws = (float*)d_ws;

    float* proj   = ws;                                    // 4096*864
    float* delta  = proj + (size_t)NROWS * NTOT;           // 4096*256
    float* deltal = delta + (size_t)NROWS * D_INN;         // 4096*256
    float* yb     = deltal + (size_t)NROWS * D_INN;        // 4096*256
    float* mem    = yb + (size_t)NROWS * D_INN;            // 2*128*256
    float* Kb     = mem + (size_t)BB * 128 * D_INN;        // 2*128*128
    float* Vb     = Kb + (size_t)BB * 128 * D_MEMM;        // 2*128*128
    float* Qbuf   = Vb + (size_t)BB * 128 * D_MEMM;        // 2*2*16*256*64 = 1.05M
    float* SDbuf  = Qbuf + (size_t)4 * SEG * D_INN * 64;   // 2*2*16*256
    float* cumd   = SDbuf + (size_t)4 * SEG * D_INN;       // 2*16*8*256

    hipLaunchKernelGGL(k_gemm, dim3(14, 64), dim3(256), 0, stream, x, Wx, Wq, bq, proj);
    hipLaunchKernelGGL(k_delta, dim3(NROWS), dim3(256), 0, stream,
                       proj, Wdt, bdt, Wdtl, bdtl, delta, deltal);
    hipLaunchKernelGGL(k_scan1, dim3(64, 2, 32), dim3(256), 0, stream,
                       x, proj, A, delta, deltal, Qbuf, SDbuf, cumd, mem);
    hipLaunchKernelGGL(k_scan2, dim3(64, 2, 16), dim3(256), 0, stream,
                       x, proj, A, Dp, delta, Qbuf, SDbuf, yb);
    hipLaunchKernelGGL(k_memfix, dim3(4, 16, 2), dim3(256), 0, stream,
                       A, Qbuf, SDbuf, cumd, mem);
    hipLaunchKernelGGL(k_kv, dim3(128, 2), dim3(128), 0, stream,
                       mem, Wk, bk, Wv, bv, Kb, Vb);
    hipLaunchKernelGGL(k_attn, dim3(LL, 2), dim3(256), 0, stream,
                       x, proj, yb, Kb, Vb, Wo, bo, out);
}

// Round 5
// 314.953 us; speedup vs baseline: 1.0275x; 1.0275x over previous
//
#include <hip/hip_runtime.h>
#include <math.h>

#define D_INN 256
#define D_HID 64
#define DTR 16
#define D_MEMM 128
#define BB 2
#define LL 2048
#define NROWS (BB*LL)   // 4096
#define NPROJ 736
#define NTOT 864        // 736 proj cols + 128 Q cols
#define SEG 16
#define SEGLEN (LL/SEG) // 128

typedef __attribute__((ext_vector_type(8))) short short8v;
typedef __attribute__((ext_vector_type(4))) float float4v;

static __device__ __forceinline__ unsigned short f2bf(float f) {
    unsigned int u = __float_as_uint(f);
    u += 0x7fff + ((u >> 16) & 1);   // RNE
    return (unsigned short)(u >> 16);
}

// ---------------- Kernel 1: proj = x @ [W_xproj | W_Q] (+b_Q), bf16 MFMA ----------------
__global__ __launch_bounds__(256) void k_gemm(const float* __restrict__ x,
        const float* __restrict__ Wx, const float* __restrict__ Wq,
        const float* __restrict__ bq, float* __restrict__ proj) {
    __shared__ unsigned short As[64][40];
    __shared__ unsigned short Bs[64][40];
    const int t = threadIdx.x;
    const int lane = t & 63, w = t >> 6;
    const int wr = w >> 1, wc = w & 1;
    const int row0 = blockIdx.y * 64, col0 = blockIdx.x * 64;

    float4v acc[2][2];
    #pragma unroll
    for (int i = 0; i < 2; i++)
        #pragma unroll
        for (int j = 0; j < 2; j++) acc[i][j] = (float4v)0.f;

    const int ar = t >> 2, akq = (t & 3) * 8;
    const int bk = t >> 3, bcq = (t & 7) * 8;

    for (int k0 = 0; k0 < D_INN; k0 += 32) {
        float4 a0 = *(const float4*)&x[(size_t)(row0 + ar) * D_INN + k0 + akq];
        float4 a1 = *(const float4*)&x[(size_t)(row0 + ar) * D_INN + k0 + akq + 4];
        float4 b0 = {}, b1 = {};
        int col = col0 + bcq;
        if (col + 8 <= NPROJ) {
            b0 = *(const float4*)&Wx[(size_t)(k0 + bk) * NPROJ + col];
            b1 = *(const float4*)&Wx[(size_t)(k0 + bk) * NPROJ + col + 4];
        } else if (col < NTOT) {
            b0 = *(const float4*)&Wq[(size_t)(k0 + bk) * D_MEMM + (col - NPROJ)];
            b1 = *(const float4*)&Wq[(size_t)(k0 + bk) * D_MEMM + (col - NPROJ) + 4];
        }
        __syncthreads();
        {
            unsigned short av[8] = { f2bf(a0.x), f2bf(a0.y), f2bf(a0.z), f2bf(a0.w),
                                     f2bf(a1.x), f2bf(a1.y), f2bf(a1.z), f2bf(a1.w) };
            *(short8v*)&As[ar][akq] = *(short8v*)av;
            Bs[bcq + 0][bk] = f2bf(b0.x); Bs[bcq + 1][bk] = f2bf(b0.y);
            Bs[bcq + 2][bk] = f2bf(b0.z); Bs[bcq + 3][bk] = f2bf(b0.w);
            Bs[bcq + 4][bk] = f2bf(b1.x); Bs[bcq + 5][bk] = f2bf(b1.y);
            Bs[bcq + 6][bk] = f2bf(b1.z); Bs[bcq + 7][bk] = f2bf(b1.w);
        }
        __syncthreads();
        short8v af[2], bf[2];
        const int fr = lane & 15, fk = (lane >> 4) * 8;
        af[0] = *(short8v*)&As[wr * 32 + fr][fk];
        af[1] = *(short8v*)&As[wr * 32 + 16 + fr][fk];
        bf[0] = *(short8v*)&Bs[wc * 32 + fr][fk];
        bf[1] = *(short8v*)&Bs[wc * 32 + 16 + fr][fk];
        #pragma unroll
        for (int i = 0; i < 2; i++)
            #pragma unroll
            for (int j = 0; j < 2; j++)
                acc[i][j] = __builtin_amdgcn_mfma_f32_16x16x32_bf16(af[i], bf[j], acc[i][j], 0, 0, 0);
    }
    #pragma unroll
    for (int i = 0; i < 2; i++)
        #pragma unroll
        for (int j = 0; j < 2; j++)
            #pragma unroll
            for (int e = 0; e < 4; e++) {
                int rr = row0 + wr * 32 + i * 16 + (lane >> 4) * 4 + e;
                int cc = col0 + wc * 32 + j * 16 + (lane & 15);
                if (cc < NTOT) {
                    float v = acc[i][j][e];
                    if (cc >= NPROJ) v += bq[cc - NPROJ];
                    proj[(size_t)rr * NTOT + cc] = v;
                }
            }
}

// ---------------- Kernel 2: delta / delta_l = softplus(dt @ W + b) ----------------
__global__ __launch_bounds__(256) void k_delta(const float* __restrict__ proj,
        const float* __restrict__ Wdt, const float* __restrict__ bdt,
        const float* __restrict__ Wdtl, const float* __restrict__ bdtl,
        float* __restrict__ delta, float* __restrict__ deltal) {
    __shared__ float sdt[16], sdtl[16];
    int row = blockIdx.x;
    int t = threadIdx.x;
    if (t < 16) sdt[t] = proj[(size_t)row * NTOT + 704 + t];
    else if (t < 32) sdtl[t - 16] = proj[(size_t)row * NTOT + 720 + (t - 16)];
    __syncthreads();
    float a1 = bdt[t], a2 = bdtl[t];
    #pragma unroll
    for (int r = 0; r < DTR; r++) {
        a1 += sdt[r] * Wdt[r * D_INN + t];
        a2 += sdtl[r] * Wdtl[r * D_INN + t];
    }
    delta[(size_t)row * D_INN + t]  = (a1 > 20.f) ? a1 : log1pf(expf(a1));
    deltal[(size_t)row * D_INN + t] = (a2 > 20.f) ? a2 : log1pf(expf(a2));
}

// ---------------- Kernel 3a: pass 1 — per-segment (sumδ, Q); scan1 also checkpoints ----
__global__ __launch_bounds__(256) void k_scan1(const float* __restrict__ x,
        const float* __restrict__ proj, const float* __restrict__ A,
        const float* __restrict__ delta, const float* __restrict__ deltal,
        float* __restrict__ Qbuf, float* __restrict__ SDbuf,
        float* __restrict__ cumd, float* __restrict__ mem) {
    __shared__ float Bsh[2][16][64];
    __shared__ float dus[2][16][8];
    const int t = threadIdx.x;
    const int w = t >> 6, n = t & 63;
    const int b = blockIdx.y;
    const int scan = blockIdx.z >> 4, seg = blockIdx.z & 15;
    const int d0 = blockIdx.x * 4, d = d0 + w;
    const size_t rowbase = (size_t)b * LL + (size_t)seg * SEGLEN;
    const float* dsel = (scan == 0 ? delta : deltal);
    const int cB = (scan == 0) ? 0 : 64;
    const float Aln = A[d * D_HID + n] * 1.44269504f;
    const int lli = t >> 4, lc4 = (t & 15) * 4;

    float4 nB = {}, du0 = {}, du1 = {};
    nB = *(const float4*)&proj[(rowbase + lli) * NTOT + cB + lc4];
    if (t < 16) {
        float4 dv4 = *(const float4*)&dsel[(rowbase + t) * D_INN + d0];
        float4 uv4 = *(const float4*)&x[(rowbase + t) * D_INN + d0];
        du0 = make_float4(dv4.x, dv4.x * uv4.x, dv4.y, dv4.y * uv4.y);
        du1 = make_float4(dv4.z, dv4.z * uv4.z, dv4.w, dv4.w * uv4.w);
    }
    *(float4*)&Bsh[0][lli][lc4] = nB;
    if (t < 16) { *(float4*)&dus[0][t][0] = du0; *(float4*)&dus[0][t][4] = du1; }
    __syncthreads();

    float s = 0.f, sd = 0.f;
    for (int c = 0; c < SEGLEN / 16; ++c) {
        const int cur = c & 1;
        const bool hn = (c + 1 < SEGLEN / 16);
        if (hn) {
            size_t row = rowbase + (c + 1) * 16;
            nB = *(const float4*)&proj[(row + lli) * NTOT + cB + lc4];
            if (t < 16) {
                float4 dv4 = *(const float4*)&dsel[(row + t) * D_INN + d0];
                float4 uv4 = *(const float4*)&x[(row + t) * D_INN + d0];
                du0 = make_float4(dv4.x, dv4.x * uv4.x, dv4.y, dv4.y * uv4.y);
                du1 = make_float4(dv4.z, dv4.z * uv4.z, dv4.w, dv4.w * uv4.w);
            }
        }
        #pragma unroll
        for (int li = 0; li < 16; ++li) {
            float2 dp = *(const float2*)&dus[cur][li][2 * w];
            float Bv = Bsh[cur][li][n];
            float dA = exp2f(dp.x * Aln);
            s = fmaf(dA, s, dp.y * Bv);
            sd += dp.x;
            if (scan == 1 && li == 0) {
                float v = s;
                #pragma unroll
                for (int off = 32; off >= 1; off >>= 1) v += __shfl_xor(v, off);
                if (n == 0) {
                    int k = seg * 8 + c;
                    mem[((size_t)b * 128 + k) * D_INN + d] = v;
                    cumd[(((size_t)b * SEG + seg) * 8 + c) * D_INN + d] = sd;
                }
            }
        }
        if (hn) {
            const int nxt = cur ^ 1;
            *(float4*)&Bsh[nxt][lli][lc4] = nB;
            if (t < 16) { *(float4*)&dus[nxt][t][0] = du0; *(float4*)&dus[nxt][t][4] = du1; }
        }
        __syncthreads();
    }
    Qbuf[((((size_t)scan * 2 + b) * SEG + seg) * D_INN + d) * 64 + n] = s;
    if (n == 0) SDbuf[(((size_t)scan * 2 + b) * SEG + seg) * D_INN + d] = sd;
}

// ---------------- Kernel 3b: pass 2 — scan 0 only, emit y ----------------
__global__ __launch_bounds__(256) void k_scan2(const float* __restrict__ x,
        const float* __restrict__ proj, const float* __restrict__ A,
        const float* __restrict__ Dp, const float* __restrict__ delta,
        const float* __restrict__ Qbuf, const float* __restrict__ SDbuf,
        float* __restrict__ y) {
    __shared__ float Bsh[2][8][64];
    __shared__ float Csh[2][8][64];
    __shared__ float dus[2][8][8];
    __shared__ float xs[2][8][4];
    __shared__ float rbuf[4][8][65];
    const int t = threadIdx.x;
    const int w = t >> 6, n = t & 63;
    const int b = blockIdx.y, seg = blockIdx.z;
    const int d0 = blockIdx.x * 4, d = d0 + w;
    const size_t rowbase = (size_t)b * LL + (size_t)seg * SEGLEN;
    const float Aln = A[d * D_HID + n] * 1.44269504f;
    const float Dpv = Dp[d];
    const int lli = (t & 127) >> 4, lc4 = (t & 15) * 4;
    const bool isB = (t < 128);
    const int rli = n >> 3, g = n & 7;

    float s = 0.f;
    for (int k = 0; k < seg; ++k) {
        float sdk = SDbuf[(((size_t)b * SEG + k) * D_INN + d)];
        float Qk = Qbuf[(((size_t)b * SEG + k) * D_INN + d) * 64 + n];
        s = fmaf(exp2f(sdk * Aln), s, Qk);
    }

    float4 nT = {}, du0 = {}, du1 = {}, nU = {};
    {
        size_t row = rowbase + lli;
        if (isB) nT = *(const float4*)&proj[row * NTOT + lc4];
        else nT = *(const float4*)&proj[row * NTOT + 128 + lc4];
        if (t < 8) {
            float4 dv4 = *(const float4*)&delta[(rowbase + t) * D_INN + d0];
            nU = *(const float4*)&x[(rowbase + t) * D_INN + d0];
            du0 = make_float4(dv4.x, dv4.x * nU.x, dv4.y, dv4.y * nU.y);
            du1 = make_float4(dv4.z, dv4.z * nU.z, dv4.w, dv4.w * nU.w);
        }
    }
    if (isB) *(float4*)&Bsh[0][lli][lc4] = nT;
    else *(float4*)&Csh[0][lli][lc4] = nT;
    if (t < 8) {
        *(float4*)&dus[0][t][0] = du0; *(float4*)&dus[0][t][4] = du1;
        *(float4*)&xs[0][t][0] = nU;
    }
    __syncthreads();

    for (int c = 0; c < SEGLEN / 8; ++c) {
        const int cur = c & 1;
        const bool hn = (c + 1 < SEGLEN / 8);
        if (hn) {
            size_t row = rowbase + (c + 1) * 8 + lli;
            if (isB) nT = *(const float4*)&proj[row * NTOT + lc4];
            else nT = *(const float4*)&proj[row * NTOT + 128 + lc4];
            if (t < 8) {
                size_t r2 = rowbase + (c + 1) * 8 + t;
                float4 dv4 = *(const float4*)&delta[r2 * D_INN + d0];
                nU = *(const float4*)&x[r2 * D_INN + d0];
                du0 = make_float4(dv4.x, dv4.x * nU.x, dv4.y, dv4.y * nU.y);
                du1 = make_float4(dv4.z, dv4.z * nU.z, dv4.w, dv4.w * nU.w);
            }
        }
        #pragma unroll
        for (int li = 0; li < 8; ++li) {
            float2 dp = *(const float2*)&dus[cur][li][2 * w];
            float Bv = Bsh[cur][li][n];
            float dA = exp2f(dp.x * Aln);
            s = fmaf(dA, s, dp.y * Bv);
            rbuf[w][li][n] = s * Csh[cur][li][n];
        }
        {
            float acc = 0.f;
            #pragma unroll
            for (int j = 0; j < 8; ++j) acc += rbuf[w][rli][g * 8 + j];
            acc += __shfl_xor(acc, 1);
            acc += __shfl_xor(acc, 2);
            acc += __shfl_xor(acc, 4);
            if (g == 0) {
                float xv = xs[cur][rli][w];
                size_t row = rowbase + c * 8 + rli;
                y[row * D_INN + d] = acc + xv * Dpv;
            }
        }
        if (hn) {
            const int nxt = cur ^ 1;
            if (isB) *(float4*)&Bsh[nxt][lli][lc4] = nT;
            else *(float4*)&Csh[nxt][lli][lc4] = nT;
            if (t < 8) {
                *(float4*)&dus[nxt][t][0] = du0; *(float4*)&dus[nxt][t][4] = du1;
                *(float4*)&xs[nxt][t][0] = nU;
            }
        }
        __syncthreads();
    }
}

// ---------------- Kernel 3c: mem fixup — carry s_in across segments, apply corrections ----
// grid (64 dtiles, 2 b); block 256 = 4 waves; wave w owns d = d0+w, lane n.
__global__ __launch_bounds__(256) void k_memfix(const float* __restrict__ A,
        const float* __restrict__ Qbuf, const float* __restrict__ SDbuf,
        const float* __restrict__ cumd, float* __restrict__ mem) {
    const int t = threadIdx.x, w = t >> 6, n = t & 63;
    const int b = blockIdx.y;
    const int d = blockIdx.x * 4 + w;
    const float Aln = A[d * D_HID + n] * 1.44269504f;
    float s_in = 0.f;   // scan=1 state entering current segment (per lane n)
    for (int seg = 0; seg < SEG; ++seg) {
        if (seg > 0) {
            #pragma unroll
            for (int ck = 0; ck < 8; ++ck) {
                float cum = cumd[(((size_t)b * SEG + seg) * 8 + ck) * D_INN + d];
                float v = exp2f(cum * Aln) * s_in;
                #pragma unroll
                for (int off = 32; off >= 1; off >>= 1) v += __shfl_xor(v, off);
                if (n == 0) mem[((size_t)b * 128 + seg * 8 + ck) * D_INN + d] += v;
            }
        }
        float sdk = SDbuf[((size_t)(2 + b) * SEG + seg) * D_INN + d];
        float Qk = Qbuf[(((size_t)(2 + b) * SEG + seg) * D_INN + d) * 64 + n];
        s_in = fmaf(exp2f(sdk * Aln), s_in, Qk);
    }
}

// ---------------- Kernel 4: K, V = memory @ W_K/V + b ----------------
__global__ __launch_bounds__(128) void k_kv(const float* __restrict__ mem,
        const float* __restrict__ Wk, const float* __restrict__ bk,
        const float* __restrict__ Wv, const float* __restrict__ bv,
        float* __restrict__ K, float* __restrict__ V) {
    __shared__ float mrow[256];
    int k = blockIdx.x, b = blockIdx.y;
    int t = threadIdx.x;
    const float* mr = mem + ((size_t)b * 128 + k) * D_INN;
    mrow[t] = mr[t];
    mrow[t + 128] = mr[t + 128];
    __syncthreads();
    float aK = bk[t], aV = bv[t];
    for (int dd = 0; dd < D_INN; dd++) {
        float m = mrow[dd];
        aK += m * Wk[dd * D_MEMM + t];
        aV += m * Wv[dd * D_MEMM + t];
    }
    K[((size_t)b * 128 + k) * D_MEMM + t] = aK;
    V[((size_t)b * 128 + k) * D_MEMM + t] = aV;
}

// ---------------- Kernel 5: attention + epilogue ----------------
__global__ __launch_bounds__(256) void k_attn(const float* __restrict__ x,
        const float* __restrict__ proj, const float* __restrict__ y,
        const float* __restrict__ K, const float* __restrict__ V,
        const float* __restrict__ Wo, const float* __restrict__ bo,
        float* __restrict__ out) {
    __shared__ float q[128], part[2][128], sc[128], att[128];
    __shared__ float red[4];
    int l = blockIdx.x, b = blockIdx.y;
    size_t row = (size_t)b * LL + l;
    int t = threadIdx.x;
    if (t < 128) q[t] = proj[row * NTOT + NPROJ + t];
    __syncthreads();
    {
        int kk = t & 127, h = t >> 7;
        const float* Kr = K + ((size_t)b * 128 + kk) * D_MEMM + h * 64;
        const float* qh = q + h * 64;
        float a = 0.f;
        for (int m = 0; m < 64; m++) a += qh[m] * Kr[m];
        part[h][kk] = a;
    }
    __syncthreads();
    float scv = 0.f;
    if (t < 128) scv = (part[0][t] + part[1][t]) * 0.125f;
    float v = (t < 128) ? scv : -3.4e38f;
    #pragma unroll
    for (int o = 1; o < 64; o <<= 1) v = fmaxf(v, __shfl_xor(v, o));
    if ((t & 63) == 0 && t < 128) red[t >> 6] = v;
    __syncthreads();
    float mx = fmaxf(red[0], red[1]);
    float ex = 0.f;
    if (t < 128) { ex = expf(scv - mx); sc[t] = ex; }
    float sv = (t < 128) ? ex : 0.f;
    #pragma unroll
    for (int o = 1; o < 64; o <<= 1) sv += __shfl_xor(sv, o);
    if ((t & 63) == 0 && t < 128) red[2 + (t >> 6)] = sv;
    __syncthreads();
    float denom = red[2] + red[3];
    {
        int m = t & 127, h = t >> 7;
        const float* Vb = V + (size_t)b * 128 * D_MEMM + m + (size_t)h * 64 * D_MEMM;
        const float* sch = sc + h * 64;
        float a = 0.f;
        for (int k = 0; k < 64; k++) a += sch[k] * Vb[(size_t)k * D_MEMM];
        part[h][m] = a;
    }
    __syncthreads();
    if (t < 128) att[t] = (part[0][t] + part[1][t]) / denom;
    __syncthreads();
    float acc = bo[t];
    for (int m = 0; m < 128; m++) acc += att[m] * Wo[m * D_INN + t];
    float Ev = proj[row * NTOT + 192 + t];
    float Fv = proj[row * NTOT + 448 + t];
    out[row * D_INN + t] = y[row * D_INN + t] + acc * Ev + x[row * D_INN + t] * Fv;
}

extern "C" void kernel_launch(void* const* d_in, const int* in_sizes, int n_in,
                              void* d_out, int out_size, void* d_ws, size_t ws_size,
                              hipStream_t stream) {
    const float* x    = (const float*)d_in[0];
    const float* Wx   = (const float*)d_in[1];
    const float* Wdt  = (const float*)d_in[2];
    const float* bdt  = (const float*)d_in[3];
    const float* Wdtl = (const float*)d_in[4];
    const float* bdtl = (const float*)d_in[5];
    const float* A    = (const float*)d_in[6];
    const float* Dp   = (const float*)d_in[7];
    const float* Wq   = (const float*)d_in[8];
    const float* bq   = (const float*)d_in[9];
    const float* Wk   = (const float*)d_in[10];
    const float* bk   = (const float*)d_in[11];
    const float* Wv   = (const float*)d_in[12];
    const float* bv   = (const float*)d_in[13];
    const float* Wo   = (const float*)d_in[14];
    const float* bo   = (const float*)d_in[15];
    float* out = (float*)d_out;
    float* ws = (float*)d_ws;

    float* proj   = ws;                                    // 4096*864
    float* delta  = proj + (size_t)NROWS * NTOT;           // 4096*256
    float* deltal = delta + (size_t)NROWS * D_INN;         // 4096*256
    float* yb     = deltal + (size_t)NROWS * D_INN;        // 4096*256
    float* mem    = yb + (size_t)NROWS * D_INN;            // 2*128*256
    float* Kb     = mem + (size_t)BB * 128 * D_INN;        // 2*128*128
    float* Vb     = Kb + (size_t)BB * 128 * D_MEMM;        // 2*128*128
    float* Qbuf   = Vb + (size_t)BB * 128 * D_MEMM;        // 4*16*256*64
    float* SDbuf  = Qbuf + (size_t)4 * SEG * D_INN * 64;   // 4*16*256
    float* cumd   = SDbuf + (size_t)4 * SEG * D_INN;       // 2*16*8*256

    hipLaunchKernelGGL(k_gemm, dim3(14, 64), dim3(256), 0, stream, x, Wx, Wq, bq, proj);
    hipLaunchKernelGGL(k_delta, dim3(NROWS), dim3(256), 0, stream,
                       proj, Wdt, bdt, Wdtl, bdtl, delta, deltal);
    hipLaunchKernelGGL(k_scan1, dim3(64, 2, 32), dim3(256), 0, stream,
                       x, proj, A, delta, deltal, Qbuf, SDbuf, cumd, mem);
    hipLaunchKernelGGL(k_scan2, dim3(64, 2, 16), dim3(256), 0, stream,
                       x, proj, A, Dp, delta, Qbuf, SDbuf, yb);
    hipLaunchKernelGGL(k_memfix, dim3(64, 2), dim3(256), 0, stream,
                       A, Qbuf, SDbuf, cumd, mem);
    hipLaunchKernelGGL(k_kv, dim3(128, 2), dim3(128), 0, stream,
                       mem, Wk, bk, Wv, bv, Kb, Vb);
    hipLaunchKernelGGL(k_attn, dim3(LL, 2), dim3(256), 0, stream,
                       x, proj, yb, Kb, Vb, Wo, bo, out);
}

// Round 6
// 241.254 us; speedup vs baseline: 1.3413x; 1.3055x over previous
//
#include <hip/hip_runtime.h>
#include <math.h>

#define D_INN 256
#define D_HID 64
#define DTR 16
#define D_MEMM 128
#define BB 2
#define LL 2048
#define NROWS (BB*LL)   // 4096
#define NPROJ 736
#define NTOT 864        // 736 proj cols + 128 Q cols
#define SEG 16
#define SEGLEN (LL/SEG) // 128

typedef __attribute__((ext_vector_type(8))) short short8v;
typedef __attribute__((ext_vector_type(4))) float float4v;

static __device__ __forceinline__ unsigned short f2bf(float f) {
    unsigned int u = __float_as_uint(f);
    u += 0x7fff + ((u >> 16) & 1);   // RNE
    return (unsigned short)(u >> 16);
}

// ---------------- Kernel 1: proj = x @ [W_xproj | W_Q] (+b_Q), bf16 MFMA ----------------
__global__ __launch_bounds__(256) void k_gemm(const float* __restrict__ x,
        const float* __restrict__ Wx, const float* __restrict__ Wq,
        const float* __restrict__ bq, float* __restrict__ proj) {
    __shared__ unsigned short As[64][40];
    __shared__ unsigned short Bs[64][40];
    const int t = threadIdx.x;
    const int lane = t & 63, w = t >> 6;
    const int wr = w >> 1, wc = w & 1;
    const int row0 = blockIdx.y * 64, col0 = blockIdx.x * 64;

    float4v acc[2][2];
    #pragma unroll
    for (int i = 0; i < 2; i++)
        #pragma unroll
        for (int j = 0; j < 2; j++) acc[i][j] = (float4v)0.f;

    const int ar = t >> 2, akq = (t & 3) * 8;
    const int bk = t >> 3, bcq = (t & 7) * 8;

    for (int k0 = 0; k0 < D_INN; k0 += 32) {
        float4 a0 = *(const float4*)&x[(size_t)(row0 + ar) * D_INN + k0 + akq];
        float4 a1 = *(const float4*)&x[(size_t)(row0 + ar) * D_INN + k0 + akq + 4];
        float4 b0 = {}, b1 = {};
        int col = col0 + bcq;
        if (col + 8 <= NPROJ) {
            b0 = *(const float4*)&Wx[(size_t)(k0 + bk) * NPROJ + col];
            b1 = *(const float4*)&Wx[(size_t)(k0 + bk) * NPROJ + col + 4];
        } else if (col < NTOT) {
            b0 = *(const float4*)&Wq[(size_t)(k0 + bk) * D_MEMM + (col - NPROJ)];
            b1 = *(const float4*)&Wq[(size_t)(k0 + bk) * D_MEMM + (col - NPROJ) + 4];
        }
        __syncthreads();
        {
            unsigned short av[8] = { f2bf(a0.x), f2bf(a0.y), f2bf(a0.z), f2bf(a0.w),
                                     f2bf(a1.x), f2bf(a1.y), f2bf(a1.z), f2bf(a1.w) };
            *(short8v*)&As[ar][akq] = *(short8v*)av;
            Bs[bcq + 0][bk] = f2bf(b0.x); Bs[bcq + 1][bk] = f2bf(b0.y);
            Bs[bcq + 2][bk] = f2bf(b0.z); Bs[bcq + 3][bk] = f2bf(b0.w);
            Bs[bcq + 4][bk] = f2bf(b1.x); Bs[bcq + 5][bk] = f2bf(b1.y);
            Bs[bcq + 6][bk] = f2bf(b1.z); Bs[bcq + 7][bk] = f2bf(b1.w);
        }
        __syncthreads();
        short8v af[2], bf[2];
        const int fr = lane & 15, fk = (lane >> 4) * 8;
        af[0] = *(short8v*)&As[wr * 32 + fr][fk];
        af[1] = *(short8v*)&As[wr * 32 + 16 + fr][fk];
        bf[0] = *(short8v*)&Bs[wc * 32 + fr][fk];
        bf[1] = *(short8v*)&Bs[wc * 32 + 16 + fr][fk];
        #pragma unroll
        for (int i = 0; i < 2; i++)
            #pragma unroll
            for (int j = 0; j < 2; j++)
                acc[i][j] = __builtin_amdgcn_mfma_f32_16x16x32_bf16(af[i], bf[j], acc[i][j], 0, 0, 0);
    }
    #pragma unroll
    for (int i = 0; i < 2; i++)
        #pragma unroll
        for (int j = 0; j < 2; j++)
            #pragma unroll
            for (int e = 0; e < 4; e++) {
                int rr = row0 + wr * 32 + i * 16 + (lane >> 4) * 4 + e;
                int cc = col0 + wc * 32 + j * 16 + (lane & 15);
                if (cc < NTOT) {
                    float v = acc[i][j][e];
                    if (cc >= NPROJ) v += bq[cc - NPROJ];
                    proj[(size_t)rr * NTOT + cc] = v;
                }
            }
}

// ---------------- Kernel 2: delta / delta_l = softplus(dt @ W + b) ----------------
__global__ __launch_bounds__(256) void k_delta(const float* __restrict__ proj,
        const float* __restrict__ Wdt, const float* __restrict__ bdt,
        const float* __restrict__ Wdtl, const float* __restrict__ bdtl,
        float* __restrict__ delta, float* __restrict__ deltal) {
    __shared__ float sdt[16], sdtl[16];
    int row = blockIdx.x;
    int t = threadIdx.x;
    if (t < 16) sdt[t] = proj[(size_t)row * NTOT + 704 + t];
    else if (t < 32) sdtl[t - 16] = proj[(size_t)row * NTOT + 720 + (t - 16)];
    __syncthreads();
    float a1 = bdt[t], a2 = bdtl[t];
    #pragma unroll
    for (int r = 0; r < DTR; r++) {
        a1 += sdt[r] * Wdt[r * D_INN + t];
        a2 += sdtl[r] * Wdtl[r * D_INN + t];
    }
    delta[(size_t)row * D_INN + t]  = (a1 > 20.f) ? a1 : log1pf(expf(a1));
    deltal[(size_t)row * D_INN + t] = (a2 > 20.f) ? a2 : log1pf(expf(a2));
}

// ---------------- Kernel 3a: pass 1 — per-segment (sumδ, Q); scan1 also checkpoints ----
__global__ __launch_bounds__(256) void k_scan1(const float* __restrict__ x,
        const float* __restrict__ proj, const float* __restrict__ A,
        const float* __restrict__ delta, const float* __restrict__ deltal,
        float* __restrict__ Qbuf, float* __restrict__ SDbuf,
        float* __restrict__ cumd, float* __restrict__ mem) {
    __shared__ float Bsh[2][16][64];
    __shared__ float dus[2][16][8];
    const int t = threadIdx.x;
    const int w = t >> 6, n = t & 63;
    const int b = blockIdx.y;
    const int scan = blockIdx.z >> 4, seg = blockIdx.z & 15;
    const int d0 = blockIdx.x * 4, d = d0 + w;
    const size_t rowbase = (size_t)b * LL + (size_t)seg * SEGLEN;
    const float* dsel = (scan == 0 ? delta : deltal);
    const int cB = (scan == 0) ? 0 : 64;
    const float Aln = A[d * D_HID + n] * 1.44269504f;
    const int lli = t >> 4, lc4 = (t & 15) * 4;

    float4 nB = {}, du0 = {}, du1 = {};
    nB = *(const float4*)&proj[(rowbase + lli) * NTOT + cB + lc4];
    if (t < 16) {
        float4 dv4 = *(const float4*)&dsel[(rowbase + t) * D_INN + d0];
        float4 uv4 = *(const float4*)&x[(rowbase + t) * D_INN + d0];
        du0 = make_float4(dv4.x, dv4.x * uv4.x, dv4.y, dv4.y * uv4.y);
        du1 = make_float4(dv4.z, dv4.z * uv4.z, dv4.w, dv4.w * uv4.w);
    }
    *(float4*)&Bsh[0][lli][lc4] = nB;
    if (t < 16) { *(float4*)&dus[0][t][0] = du0; *(float4*)&dus[0][t][4] = du1; }
    __syncthreads();

    float s = 0.f, sd = 0.f;
    for (int c = 0; c < SEGLEN / 16; ++c) {
        const int cur = c & 1;
        const bool hn = (c + 1 < SEGLEN / 16);
        if (hn) {
            size_t row = rowbase + (c + 1) * 16;
            nB = *(const float4*)&proj[(row + lli) * NTOT + cB + lc4];
            if (t < 16) {
                float4 dv4 = *(const float4*)&dsel[(row + t) * D_INN + d0];
                float4 uv4 = *(const float4*)&x[(row + t) * D_INN + d0];
                du0 = make_float4(dv4.x, dv4.x * uv4.x, dv4.y, dv4.y * uv4.y);
                du1 = make_float4(dv4.z, dv4.z * uv4.z, dv4.w, dv4.w * uv4.w);
            }
        }
        #pragma unroll
        for (int li = 0; li < 16; ++li) {
            float2 dp = *(const float2*)&dus[cur][li][2 * w];
            float Bv = Bsh[cur][li][n];
            float dA = exp2f(dp.x * Aln);
            s = fmaf(dA, s, dp.y * Bv);
            sd += dp.x;
            if (scan == 1 && li == 0) {
                float v = s;
                #pragma unroll
                for (int off = 32; off >= 1; off >>= 1) v += __shfl_xor(v, off);
                if (n == 0) {
                    int k = seg * 8 + c;
                    mem[((size_t)b * 128 + k) * D_INN + d] = v;
                    cumd[(((size_t)b * SEG + seg) * 8 + c) * D_INN + d] = sd;
                }
            }
        }
        if (hn) {
            const int nxt = cur ^ 1;
            *(float4*)&Bsh[nxt][lli][lc4] = nB;
            if (t < 16) { *(float4*)&dus[nxt][t][0] = du0; *(float4*)&dus[nxt][t][4] = du1; }
        }
        __syncthreads();
    }
    Qbuf[((((size_t)scan * 2 + b) * SEG + seg) * D_INN + d) * 64 + n] = s;
    if (n == 0) SDbuf[(((size_t)scan * 2 + b) * SEG + seg) * D_INN + d] = sd;
}

// ---------------- Kernel 3b: pass 2 — scan 0 only, emit y ----------------
__global__ __launch_bounds__(256) void k_scan2(const float* __restrict__ x,
        const float* __restrict__ proj, const float* __restrict__ A,
        const float* __restrict__ Dp, const float* __restrict__ delta,
        const float* __restrict__ Qbuf, const float* __restrict__ SDbuf,
        float* __restrict__ y) {
    __shared__ float Bsh[2][8][64];
    __shared__ float Csh[2][8][64];
    __shared__ float dus[2][8][8];
    __shared__ float xs[2][8][4];
    __shared__ float rbuf[4][8][65];
    const int t = threadIdx.x;
    const int w = t >> 6, n = t & 63;
    const int b = blockIdx.y, seg = blockIdx.z;
    const int d0 = blockIdx.x * 4, d = d0 + w;
    const size_t rowbase = (size_t)b * LL + (size_t)seg * SEGLEN;
    const float Aln = A[d * D_HID + n] * 1.44269504f;
    const float Dpv = Dp[d];
    const int lli = (t & 127) >> 4, lc4 = (t & 15) * 4;
    const bool isB = (t < 128);
    const int rli = n >> 3, g = n & 7;

    float s = 0.f;
    for (int k = 0; k < seg; ++k) {
        float sdk = SDbuf[(((size_t)b * SEG + k) * D_INN + d)];
        float Qk = Qbuf[(((size_t)b * SEG + k) * D_INN + d) * 64 + n];
        s = fmaf(exp2f(sdk * Aln), s, Qk);
    }

    float4 nT = {}, du0 = {}, du1 = {}, nU = {};
    {
        size_t row = rowbase + lli;
        if (isB) nT = *(const float4*)&proj[row * NTOT + lc4];
        else nT = *(const float4*)&proj[row * NTOT + 128 + lc4];
        if (t < 8) {
            float4 dv4 = *(const float4*)&delta[(rowbase + t) * D_INN + d0];
            nU = *(const float4*)&x[(rowbase + t) * D_INN + d0];
            du0 = make_float4(dv4.x, dv4.x * nU.x, dv4.y, dv4.y * nU.y);
            du1 = make_float4(dv4.z, dv4.z * nU.z, dv4.w, dv4.w * nU.w);
        }
    }
    if (isB) *(float4*)&Bsh[0][lli][lc4] = nT;
    else *(float4*)&Csh[0][lli][lc4] = nT;
    if (t < 8) {
        *(float4*)&dus[0][t][0] = du0; *(float4*)&dus[0][t][4] = du1;
        *(float4*)&xs[0][t][0] = nU;
    }
    __syncthreads();

    for (int c = 0; c < SEGLEN / 8; ++c) {
        const int cur = c & 1;
        const bool hn = (c + 1 < SEGLEN / 8);
        if (hn) {
            size_t row = rowbase + (c + 1) * 8 + lli;
            if (isB) nT = *(const float4*)&proj[row * NTOT + lc4];
            else nT = *(const float4*)&proj[row * NTOT + 128 + lc4];
            if (t < 8) {
                size_t r2 = rowbase + (c + 1) * 8 + t;
                float4 dv4 = *(const float4*)&delta[r2 * D_INN + d0];
                nU = *(const float4*)&x[r2 * D_INN + d0];
                du0 = make_float4(dv4.x, dv4.x * nU.x, dv4.y, dv4.y * nU.y);
                du1 = make_float4(dv4.z, dv4.z * nU.z, dv4.w, dv4.w * nU.w);
            }
        }
        #pragma unroll
        for (int li = 0; li < 8; ++li) {
            float2 dp = *(const float2*)&dus[cur][li][2 * w];
            float Bv = Bsh[cur][li][n];
            float dA = exp2f(dp.x * Aln);
            s = fmaf(dA, s, dp.y * Bv);
            rbuf[w][li][n] = s * Csh[cur][li][n];
        }
        {
            float acc = 0.f;
            #pragma unroll
            for (int j = 0; j < 8; ++j) acc += rbuf[w][rli][g * 8 + j];
            acc += __shfl_xor(acc, 1);
            acc += __shfl_xor(acc, 2);
            acc += __shfl_xor(acc, 4);
            if (g == 0) {
                float xv = xs[cur][rli][w];
                size_t row = rowbase + c * 8 + rli;
                y[row * D_INN + d] = acc + xv * Dpv;
            }
        }
        if (hn) {
            const int nxt = cur ^ 1;
            if (isB) *(float4*)&Bsh[nxt][lli][lc4] = nT;
            else *(float4*)&Csh[nxt][lli][lc4] = nT;
            if (t < 8) {
                *(float4*)&dus[nxt][t][0] = du0; *(float4*)&dus[nxt][t][4] = du1;
                *(float4*)&xs[nxt][t][0] = nU;
            }
        }
        __syncthreads();
    }
}

// ---------------- Kernel 3c-1: segment-boundary states for scan=1 ----------------
// grid (64, 2); wave w -> d = d0+w, lane n. Fully unrolled so loads issue early.
__global__ __launch_bounds__(256) void k_sin(const float* __restrict__ A,
        const float* __restrict__ Qbuf, const float* __restrict__ SDbuf,
        float* __restrict__ Sin) {
    const int t = threadIdx.x, w = t >> 6, n = t & 63;
    const int b = blockIdx.y;
    const int d = blockIdx.x * 4 + w;
    const float Aln = A[d * D_HID + n] * 1.44269504f;
    float s = 0.f;
    #pragma unroll
    for (int seg = 0; seg < SEG; ++seg) {
        if (seg > 0) Sin[(((size_t)b * SEG + seg) * D_INN + d) * 64 + n] = s;
        float sdk = SDbuf[((size_t)(2 + b) * SEG + seg) * D_INN + d];
        float Qk = Qbuf[(((size_t)(2 + b) * SEG + seg) * D_INN + d) * 64 + n];
        s = fmaf(exp2f(sdk * Aln), s, Qk);
    }
}

// ---------------- Kernel 3c-2: parallel mem correction ----------------
// grid (64 dtiles, 120 ck, 2 b); wave w -> one (d, checkpoint); k = 8 + blockIdx.y.
__global__ __launch_bounds__(256) void k_fix(const float* __restrict__ A,
        const float* __restrict__ Sin, const float* __restrict__ cumd,
        float* __restrict__ mem) {
    const int t = threadIdx.x, w = t >> 6, n = t & 63;
    const int k = 8 + blockIdx.y;             // checkpoints in segs 1..15
    const int b = blockIdx.z;
    const int d = blockIdx.x * 4 + w;
    const int seg = k >> 3;
    const float Aln = A[d * D_HID + n] * 1.44269504f;
    float cum = cumd[((size_t)b * 128 + k) * D_INN + d];
    float sv = Sin[(((size_t)b * SEG + seg) * D_INN + d) * 64 + n];
    float v = exp2f(cum * Aln) * sv;
    #pragma unroll
    for (int off = 32; off >= 1; off >>= 1) v += __shfl_xor(v, off);
    if (n == 0) mem[((size_t)b * 128 + k) * D_INN + d] += v;
}

// ---------------- Kernel 4: K, V = memory @ W_K/V + b ----------------
__global__ __launch_bounds__(128) void k_kv(const float* __restrict__ mem,
        const float* __restrict__ Wk, const float* __restrict__ bk,
        const float* __restrict__ Wv, const float* __restrict__ bv,
        float* __restrict__ K, float* __restrict__ V) {
    __shared__ float mrow[256];
    int k = blockIdx.x, b = blockIdx.y;
    int t = threadIdx.x;
    const float* mr = mem + ((size_t)b * 128 + k) * D_INN;
    mrow[t] = mr[t];
    mrow[t + 128] = mr[t + 128];
    __syncthreads();
    float aK = bk[t], aV = bv[t];
    for (int dd = 0; dd < D_INN; dd++) {
        float m = mrow[dd];
        aK += m * Wk[dd * D_MEMM + t];
        aV += m * Wv[dd * D_MEMM + t];
    }
    K[((size_t)b * 128 + k) * D_MEMM + t] = aK;
    V[((size_t)b * 128 + k) * D_MEMM + t] = aV;
}

// ---------------- Kernel 5: attention + epilogue ----------------
__global__ __launch_bounds__(256) void k_attn(const float* __restrict__ x,
        const float* __restrict__ proj, const float* __restrict__ y,
        const float* __restrict__ K, const float* __restrict__ V,
        const float* __restrict__ Wo, const float* __restrict__ bo,
        float* __restrict__ out) {
    __shared__ float q[128], part[2][128], sc[128], att[128];
    __shared__ float red[4];
    int l = blockIdx.x, b = blockIdx.y;
    size_t row = (size_t)b * LL + l;
    int t = threadIdx.x;
    if (t < 128) q[t] = proj[row * NTOT + NPROJ + t];
    __syncthreads();
    {
        int kk = t & 127, h = t >> 7;
        const float* Kr = K + ((size_t)b * 128 + kk) * D_MEMM + h * 64;
        const float* qh = q + h * 64;
        float a = 0.f;
        for (int m = 0; m < 64; m++) a += qh[m] * Kr[m];
        part[h][kk] = a;
    }
    __syncthreads();
    float scv = 0.f;
    if (t < 128) scv = (part[0][t] + part[1][t]) * 0.125f;
    float v = (t < 128) ? scv : -3.4e38f;
    #pragma unroll
    for (int o = 1; o < 64; o <<= 1) v = fmaxf(v, __shfl_xor(v, o));
    if ((t & 63) == 0 && t < 128) red[t >> 6] = v;
    __syncthreads();
    float mx = fmaxf(red[0], red[1]);
    float ex = 0.f;
    if (t < 128) { ex = expf(scv - mx); sc[t] = ex; }
    float sv = (t < 128) ? ex : 0.f;
    #pragma unroll
    for (int o = 1; o < 64; o <<= 1) sv += __shfl_xor(sv, o);
    if ((t & 63) == 0 && t < 128) red[2 + (t >> 6)] = sv;
    __syncthreads();
    float denom = red[2] + red[3];
    {
        int m = t & 127, h = t >> 7;
        const float* Vb = V + (size_t)b * 128 * D_MEMM + m + (size_t)h * 64 * D_MEMM;
        const float* sch = sc + h * 64;
        float a = 0.f;
        for (int k = 0; k < 64; k++) a += sch[k] * Vb[(size_t)k * D_MEMM];
        part[h][m] = a;
    }
    __syncthreads();
    if (t < 128) att[t] = (part[0][t] + part[1][t]) / denom;
    __syncthreads();
    float acc = bo[t];
    for (int m = 0; m < 128; m++) acc += att[m] * Wo[m * D_INN + t];
    float Ev = proj[row * NTOT + 192 + t];
    float Fv = proj[row * NTOT + 448 + t];
    out[row * D_INN + t] = y[row * D_INN + t] + acc * Ev + x[row * D_INN + t] * Fv;
}

extern "C" void kernel_launch(void* const* d_in, const int* in_sizes, int n_in,
                              void* d_out, int out_size, void* d_ws, size_t ws_size,
                              hipStream_t stream) {
    const float* x    = (const float*)d_in[0];
    const float* Wx   = (const float*)d_in[1];
    const float* Wdt  = (const float*)d_in[2];
    const float* bdt  = (const float*)d_in[3];
    const float* Wdtl = (const float*)d_in[4];
    const float* bdtl = (const float*)d_in[5];
    const float* A    = (const float*)d_in[6];
    const float* Dp   = (const float*)d_in[7];
    const float* Wq   = (const float*)d_in[8];
    const float* bq   = (const float*)d_in[9];
    const float* Wk   = (const float*)d_in[10];
    const float* bk   = (const float*)d_in[11];
    const float* Wv   = (const float*)d_in[12];
    const float* bv   = (const float*)d_in[13];
    const float* Wo   = (const float*)d_in[14];
    const float* bo   = (const float*)d_in[15];
    float* out = (float*)d_out;
    float* ws = (float*)d_ws;

    float* proj   = ws;                                    // 4096*864
    float* delta  = proj + (size_t)NROWS * NTOT;           // 4096*256
    float* deltal = delta + (size_t)NROWS * D_INN;         // 4096*256
    float* yb     = deltal + (size_t)NROWS * D_INN;        // 4096*256
    float* mem    = yb + (size_t)NROWS * D_INN;            // 2*128*256
    float* Kb     = mem + (size_t)BB * 128 * D_INN;        // 2*128*128
    float* Vb     = Kb + (size_t)BB * 128 * D_MEMM;        // 2*128*128
    float* Qbuf   = Vb + (size_t)BB * 128 * D_MEMM;        // 4*16*256*64
    float* SDbuf  = Qbuf + (size_t)4 * SEG * D_INN * 64;   // 4*16*256
    float* cumd   = SDbuf + (size_t)4 * SEG * D_INN;       // 2*16*8*256
    float* Sin    = cumd + (size_t)BB * SEG * 8 * D_INN;   // 2*16*256*64

    hipLaunchKernelGGL(k_gemm, dim3(14, 64), dim3(256), 0, stream, x, Wx, Wq, bq, proj);
    hipLaunchKernelGGL(k_delta, dim3(NROWS), dim3(256), 0, stream,
                       proj, Wdt, bdt, Wdtl, bdtl, delta, deltal);
    hipLaunchKernelGGL(k_scan1, dim3(64, 2, 32), dim3(256), 0, stream,
                       x, proj, A, delta, deltal, Qbuf, SDbuf, cumd, mem);
    hipLaunchKernelGGL(k_scan2, dim3(64, 2, 16), dim3(256), 0, stream,
                       x, proj, A, Dp, delta, Qbuf, SDbuf, yb);
    hipLaunchKernelGGL(k_sin, dim3(64, 2), dim3(256), 0, stream,
                       A, Qbuf, SDbuf, Sin);
    hipLaunchKernelGGL(k_fix, dim3(64, 120, 2), dim3(256), 0, stream,
                       A, Sin, cumd, mem);
    hipLaunchKernelGGL(k_kv, dim3(128, 2), dim3(128), 0, stream,
                       mem, Wk, bk, Wv, bv, Kb, Vb);
    hipLaunchKernelGGL(k_attn, dim3(LL, 2), dim3(256), 0, stream,
                       x, proj, yb, Kb, Vb, Wo, bo, out);
}